// Round 1
// baseline (821.075 us; speedup 1.0000x reference)
//
#include <hip/hip_runtime.h>
#include <type_traits>

typedef unsigned short u16;
typedef unsigned int   u32;
using short8 = __attribute__((ext_vector_type(8))) short;
using f32x4  = __attribute__((ext_vector_type(4))) float;

// ---------- bf16 helpers (manual RNE, no header-version dependence) ----------
__device__ __forceinline__ u16 f2bf(float f) {
  u32 u = __builtin_bit_cast(u32, f);
  u32 r = (u + 0x7FFFu + ((u >> 16) & 1u)) >> 16;
  return (u16)r;
}
__device__ __forceinline__ float bf2f(u16 h) {
  return __builtin_bit_cast(float, (u32)h << 16);
}
__device__ __forceinline__ short8 cvt8(float4 f0, float4 f1) {
  short8 r;
  r[0] = (short)f2bf(f0.x); r[1] = (short)f2bf(f0.y);
  r[2] = (short)f2bf(f0.z); r[3] = (short)f2bf(f0.w);
  r[4] = (short)f2bf(f1.x); r[5] = (short)f2bf(f1.y);
  r[6] = (short)f2bf(f1.z); r[7] = (short)f2bf(f1.w);
  return r;
}

static constexpr int NN = 8192;

// ---------- kernel 1: dinv[i] = rsqrt(1 + sum_j adj[i][j]) ----------
__global__ __launch_bounds__(256) void rowsum_k(const float* __restrict__ adj,
                                                float* __restrict__ dinv) {
  const int row = blockIdx.x;
  const float4* p = (const float4*)(adj + (size_t)row * NN);
  float s = 0.f;
#pragma unroll
  for (int i = 0; i < 8; ++i) {
    float4 v = p[threadIdx.x + i * 256];
    s += v.x + v.y + v.z + v.w;
  }
#pragma unroll
  for (int off = 32; off > 0; off >>= 1) s += __shfl_down(s, off, 64);
  __shared__ float partial[4];
  if ((threadIdx.x & 63) == 0) partial[threadIdx.x >> 6] = s;
  __syncthreads();
  if (threadIdx.x == 0)
    dinv[row] = rsqrtf(partial[0] + partial[1] + partial[2] + partial[3] + 1.0f);
}

// ---------- kernel 2: Gt[c][r] = bf16( dinv[r] * (X @ W)[r][c] ), c in [0,128)
// X: [8192][K] (float or bf16-as-u16), W: [K][C] fp32; cols c>=C -> 0.
template <typename TIN>
__global__ __launch_bounds__(256) void featmul_k(const TIN* __restrict__ X,
                                                 const float* __restrict__ W,
                                                 const float* __restrict__ dinv,
                                                 u16* __restrict__ Gt,
                                                 int K, int C) {
  __shared__ __align__(16) u16 Wt[128][128];  // [c][k] bf16, 32 KB
  __shared__ float red[4][16][32];            // per-wave transpose bounce, 8 KB
  const int tid = threadIdx.x;
  for (int idx = tid; idx < 128 * 128; idx += 256) {
    int c = idx & 127, k = idx >> 7;
    float w = (k < K && c < C) ? W[k * C + c] : 0.f;
    Wt[c][k] = f2bf(w);
  }
  __syncthreads();
  const int wv = tid >> 6, lane = tid & 63;
  const int q = lane >> 4, m16 = lane & 15;
  const int r0 = blockIdx.x * 16;   // 512 blocks cover M=8192
  const int c0 = wv * 32;           // 4 waves cover N=128
  f32x4 acc[2];
  acc[0] = {0.f, 0.f, 0.f, 0.f};
  acc[1] = {0.f, 0.f, 0.f, 0.f};
  const TIN* xrow = X + (size_t)(r0 + m16) * K;
  for (int k = 0; k < K; k += 32) {
    short8 af;
    if constexpr (std::is_same_v<TIN, float>) {
      float4 f0 = *(const float4*)(xrow + k + q * 8);
      float4 f1 = *(const float4*)(xrow + k + q * 8 + 4);
      af = cvt8(f0, f1);
    } else {
      af = __builtin_bit_cast(short8, *(const uint4*)(xrow + k + q * 8));
    }
#pragma unroll
    for (int nh = 0; nh < 2; ++nh) {
      short8 bf = *(const short8*)&Wt[c0 + nh * 16 + m16][k + q * 8];
      acc[nh] = __builtin_amdgcn_mfma_f32_16x16x32_bf16(af, bf, acc[nh], 0, 0, 0);
    }
  }
#pragma unroll
  for (int nh = 0; nh < 2; ++nh)
#pragma unroll
    for (int reg = 0; reg < 4; ++reg)
      red[wv][q * 4 + reg][nh * 16 + m16] = acc[nh][reg];
  __syncthreads();
  {
    const int cc = lane & 31, rh = lane >> 5;
    short8 t;
#pragma unroll
    for (int i = 0; i < 8; ++i) {
      int r = rh * 8 + i;
      t[i] = (short)f2bf(red[wv][r][cc] * dinv[r0 + r]);
    }
    *(uint4*)(Gt + (size_t)(c0 + cc) * NN + r0 + rh * 8) = __builtin_bit_cast(uint4, t);
  }
}

// ---------- kernel 3: the big GEMM  out = ep( dinv[r]*(adj@u + u) + bias ) ----
// adj fp32 streamed + converted in-register; u given transposed as Gt[128][8192] bf16.
// grid 256 (M-tiles of 32 rows), block 512 = 8 waves: wave = (s: K-quarter, nsl: N-half).
// Wave tile 32x64, in-block split-K over 4 quarters reduced via LDS.
template <int RELU, int OUT_F32>
__global__ __launch_bounds__(512) void gcn_gemm(const float* __restrict__ Adj,
                                                const u16* __restrict__ Gt,
                                                const float* __restrict__ dinv,
                                                const float* __restrict__ bias,
                                                u16* __restrict__ Hout,
                                                float* __restrict__ Fout) {
  const int K = NN;
  const int tid = threadIdx.x;
  const int wv = tid >> 6, lane = tid & 63;
  const int s = wv >> 1, nsl = wv & 1;
  const int q = lane >> 4, m16 = lane & 15;
  const int mbase = blockIdx.x * 32;
  const int k0 = s * 2048, kend = k0 + 2048;

  const float* arow0 = Adj + (size_t)(mbase + m16) * K;
  const float* arow1 = arow0 + (size_t)16 * K;
  const u16* brow[4];
#pragma unroll
  for (int nh = 0; nh < 4; ++nh)
    brow[nh] = Gt + (size_t)(nsl * 64 + nh * 16 + m16) * K;

  f32x4 acc[2][4];
#pragma unroll
  for (int mh = 0; mh < 2; ++mh)
#pragma unroll
    for (int nh = 0; nh < 4; ++nh) acc[mh][nh] = {0.f, 0.f, 0.f, 0.f};

  float4 araw[2][2][2];  // [buf][mh][half]
  short8 bfr[2][4];      // [buf][nh]

  auto loadf = [&](int buf, int k) {
    const float* pa0 = arow0 + k + q * 8;
    const float* pa1 = arow1 + k + q * 8;
    araw[buf][0][0] = *(const float4*)pa0;
    araw[buf][0][1] = *(const float4*)(pa0 + 4);
    araw[buf][1][0] = *(const float4*)pa1;
    araw[buf][1][1] = *(const float4*)(pa1 + 4);
#pragma unroll
    for (int nh = 0; nh < 4; ++nh)
      bfr[buf][nh] = __builtin_bit_cast(short8, *(const uint4*)(brow[nh] + k + q * 8));
  };
  auto domfma = [&](int buf) {
#pragma unroll
    for (int mh = 0; mh < 2; ++mh) {
      short8 af = cvt8(araw[buf][mh][0], araw[buf][mh][1]);
#pragma unroll
      for (int nh = 0; nh < 4; ++nh)
        acc[mh][nh] =
            __builtin_amdgcn_mfma_f32_16x16x32_bf16(af, bfr[buf][nh], acc[mh][nh], 0, 0, 0);
    }
  };

  loadf(0, k0);
  for (int k = k0; k < kend; k += 64) {
    loadf(1, k + 32);      // prefetch half-step; compiler overlaps with mfma(0)
    domfma(0);
    if (k + 64 < kend) loadf(0, k + 64);
    domfma(1);
  }

  // in-block split-K reduction: quarters 1..3 dump to LDS, quarter 0 combines.
  __shared__ float red[3][32][128];  // 48 KB
  if (s > 0) {
#pragma unroll
    for (int mh = 0; mh < 2; ++mh)
#pragma unroll
      for (int nh = 0; nh < 4; ++nh)
#pragma unroll
        for (int reg = 0; reg < 4; ++reg)
          red[s - 1][mh * 16 + q * 4 + reg][nsl * 64 + nh * 16 + m16] = acc[mh][nh][reg];
  }
  __syncthreads();
  if (s == 0) {
    if (OUT_F32 && nsl == 1) return;  // last layer only stores cols < 64
#pragma unroll
    for (int mh = 0; mh < 2; ++mh) {
#pragma unroll
      for (int nh = 0; nh < 4; ++nh) {
        const int c = nsl * 64 + nh * 16 + m16;
        const float bv = bias[c];
#pragma unroll
        for (int reg = 0; reg < 4; ++reg) {
          const int r = mh * 16 + q * 4 + reg;
          const int gr = mbase + r;
          float sum = acc[mh][nh][reg] + red[0][r][c] + red[1][r][c] + red[2][r][c];
          sum += bf2f(Gt[(size_t)c * K + gr]);  // + I @ u  (A_hat = adj + I)
          sum = dinv[gr] * sum + bv;
          if (RELU) sum = fmaxf(sum, 0.f);
          if (OUT_F32)
            Fout[(size_t)gr * 64 + c] = sum;
          else
            Hout[(size_t)gr * 128 + c] = f2bf(sum);
        }
      }
    }
  }
}

// ---------- launch ----------
extern "C" void kernel_launch(void* const* d_in, const int* in_sizes, int n_in,
                              void* d_out, int out_size, void* d_ws, size_t ws_size,
                              hipStream_t stream) {
  const float* x   = (const float*)d_in[0];  // [8192][64]
  const float* adj = (const float*)d_in[1];  // [8192][8192]
  const float* W0  = (const float*)d_in[2];  // [64][128]
  const float* b0  = (const float*)d_in[3];  // [128]
  const float* W1  = (const float*)d_in[4];  // [128][128]
  const float* b1  = (const float*)d_in[5];  // [128]
  const float* W2  = (const float*)d_in[6];  // [128][64]
  const float* b2  = (const float*)d_in[7];  // [64]
  float* out = (float*)d_out;                // [8192][64] fp32

  char* ws = (char*)d_ws;
  float* dinv = (float*)ws;                              // 32 KB
  u16* Gt     = (u16*)(ws + 32768);                      // 2 MB  [128][8192] bf16
  u16* h      = (u16*)(ws + 32768 + 2097152);            // 2 MB  [8192][128] bf16
  // total ws use ~4.2 MB

  rowsum_k<<<NN, 256, 0, stream>>>(adj, dinv);

  // layer 0: u0 = dinv ∘ (x@W0);  h = relu(dinv∘(adj@u0 + u0) + b0)
  featmul_k<float><<<NN / 16, 256, 0, stream>>>(x, W0, dinv, Gt, 64, 128);
  gcn_gemm<1, 0><<<256, 512, 0, stream>>>(adj, Gt, dinv, b0, h, nullptr);

  // layer 1
  featmul_k<u16><<<NN / 16, 256, 0, stream>>>(h, W1, dinv, Gt, 128, 128);
  gcn_gemm<1, 0><<<256, 512, 0, stream>>>(adj, Gt, dinv, b1, h, nullptr);

  // layer 2 (no relu, fp32 out, 64 cols; Gt rows 64..127 are zeros)
  featmul_k<u16><<<NN / 16, 256, 0, stream>>>(h, W2, dinv, Gt, 128, 64);
  gcn_gemm<0, 1><<<256, 512, 0, stream>>>(adj, Gt, dinv, b2, nullptr, out);
}

// Round 2
// 706.186 us; speedup vs baseline: 1.1627x; 1.1627x over previous
//
#include <hip/hip_runtime.h>
#include <type_traits>

typedef unsigned short u16;
typedef unsigned int   u32;
using short8 = __attribute__((ext_vector_type(8))) short;
using f32x4  = __attribute__((ext_vector_type(4))) float;

#define GLD_AS1 const __attribute__((address_space(1))) unsigned
#define GLD_AS3 __attribute__((address_space(3))) unsigned

static constexpr int NN = 8192;

// ---------- bf16 helpers (manual RNE) ----------
__device__ __forceinline__ u16 f2bf(float f) {
  u32 u = __builtin_bit_cast(u32, f);
  u32 r = (u + 0x7FFFu + ((u >> 16) & 1u)) >> 16;
  return (u16)r;
}
__device__ __forceinline__ float bf2f(u16 h) {
  return __builtin_bit_cast(float, (u32)h << 16);
}
__device__ __forceinline__ short8 cvt8(float4 f0, float4 f1) {
  short8 r;
  r[0] = (short)f2bf(f0.x); r[1] = (short)f2bf(f0.y);
  r[2] = (short)f2bf(f0.z); r[3] = (short)f2bf(f0.w);
  r[4] = (short)f2bf(f1.x); r[5] = (short)f2bf(f1.y);
  r[6] = (short)f2bf(f1.z); r[7] = (short)f2bf(f1.w);
  return r;
}

// ---------- kernel 1: fused rowsum + bf16 convert ----------
// dinv[i] = rsqrt(1 + sum_j adj[i][j]);  adjb = bf16(adj)
__global__ __launch_bounds__(256) void rowsum_cvt_k(const float* __restrict__ adj,
                                                    u16* __restrict__ adjb,
                                                    float* __restrict__ dinv) {
  const int row = blockIdx.x;
  const float4* p = (const float4*)(adj + (size_t)row * NN);
  uint2* w = (uint2*)(adjb + (size_t)row * NN);
  float s = 0.f;
#pragma unroll
  for (int i = 0; i < 8; ++i) {
    float4 v = p[threadIdx.x + i * 256];
    s += (v.x + v.y) + (v.z + v.w);
    uint2 o;
    o.x = (u32)f2bf(v.x) | ((u32)f2bf(v.y) << 16);
    o.y = (u32)f2bf(v.z) | ((u32)f2bf(v.w) << 16);
    w[threadIdx.x + i * 256] = o;
  }
#pragma unroll
  for (int off = 32; off > 0; off >>= 1) s += __shfl_down(s, off, 64);
  __shared__ float partial[4];
  if ((threadIdx.x & 63) == 0) partial[threadIdx.x >> 6] = s;
  __syncthreads();
  if (threadIdx.x == 0)
    dinv[row] = rsqrtf(partial[0] + partial[1] + partial[2] + partial[3] + 1.0f);
}

// ---------- kernel 2: Gt[c][r] = bf16( dinv[r] * (X @ W)[r][c] ), c in [0,128)
template <typename TIN>
__global__ __launch_bounds__(256) void featmul_k(const TIN* __restrict__ X,
                                                 const float* __restrict__ W,
                                                 const float* __restrict__ dinv,
                                                 u16* __restrict__ Gt,
                                                 int K, int C) {
  __shared__ __align__(16) u16 Wt[128][128];
  __shared__ float red[4][16][32];
  const int tid = threadIdx.x;
  for (int idx = tid; idx < 128 * 128; idx += 256) {
    int c = idx & 127, k = idx >> 7;
    float w = (k < K && c < C) ? W[k * C + c] : 0.f;
    Wt[c][k] = f2bf(w);
  }
  __syncthreads();
  const int wv = tid >> 6, lane = tid & 63;
  const int q = lane >> 4, m16 = lane & 15;
  const int r0 = blockIdx.x * 16;
  const int c0 = wv * 32;
  f32x4 acc[2];
  acc[0] = {0.f, 0.f, 0.f, 0.f};
  acc[1] = {0.f, 0.f, 0.f, 0.f};
  const TIN* xrow = X + (size_t)(r0 + m16) * K;
  for (int k = 0; k < K; k += 32) {
    short8 af;
    if constexpr (std::is_same_v<TIN, float>) {
      float4 f0 = *(const float4*)(xrow + k + q * 8);
      float4 f1 = *(const float4*)(xrow + k + q * 8 + 4);
      af = cvt8(f0, f1);
    } else {
      af = __builtin_bit_cast(short8, *(const uint4*)(xrow + k + q * 8));
    }
#pragma unroll
    for (int nh = 0; nh < 2; ++nh) {
      short8 bf = *(const short8*)&Wt[c0 + nh * 16 + m16][k + q * 8];
      acc[nh] = __builtin_amdgcn_mfma_f32_16x16x32_bf16(af, bf, acc[nh], 0, 0, 0);
    }
  }
#pragma unroll
  for (int nh = 0; nh < 2; ++nh)
#pragma unroll
    for (int reg = 0; reg < 4; ++reg)
      red[wv][q * 4 + reg][nh * 16 + m16] = acc[nh][reg];
  __syncthreads();
  {
    const int cc = lane & 31, rh = lane >> 5;
    short8 t;
#pragma unroll
    for (int i = 0; i < 8; ++i) {
      int r = rh * 8 + i;
      t[i] = (short)f2bf(red[wv][r][cc] * dinv[r0 + r]);
    }
    *(uint4*)(Gt + (size_t)(c0 + cc) * NN + r0 + rh * 8) = __builtin_bit_cast(uint4, t);
  }
}

// ---------- kernel 3: out = ep( dinv[r]*(adjb@u + u) + bias ) ----------
// A (adjb, bf16) staged via global_load_lds (swizzled, double-buffered, BK=256);
// B (Gt, 2 MB, L2-resident) direct to registers, double-buffered.
// Block 512 = 8 waves: wave = (npair 0..3, khalf 0..1). M-tile 32, full N=128,
// in-block split-K x2 reduced through LDS in the epilogue. Grid 256 (1 block/CU).
template <int RELU, int OUT_F32>
__global__ __launch_bounds__(512, 1) void gcn_gemm(const u16* __restrict__ Adjb,
                                                   const u16* __restrict__ Gt,
                                                   const float* __restrict__ dinv,
                                                   const float* __restrict__ bias,
                                                   u16* __restrict__ Hout,
                                                   float* __restrict__ Fout) {
  __shared__ __align__(16) u16 Abuf[2][32 * 256];  // 2 x 16 KB, xor-swizzled rows
  __shared__ float red[4][64][17];                 // split-K bounce, padded

  const int tid = threadIdx.x;
  const int wv = tid >> 6, lane = tid & 63;
  const int npair = wv >> 1, khalf = wv & 1;
  const int q = lane >> 4, m16 = lane & 15;
  const int mbase = blockIdx.x * 32;

  const u16* brow0 = Gt + (size_t)(npair * 32 + m16) * NN;
  const u16* brow1 = brow0 + (size_t)16 * NN;

  f32x4 acc[2][2];  // [mh][nn]
#pragma unroll
  for (int a = 0; a < 2; ++a)
#pragma unroll
    for (int b = 0; b < 2; ++b) acc[a][b] = {0.f, 0.f, 0.f, 0.f};

  short8 breg[2][2][4];  // [buf][nn][j]

  auto stageA = [&](int buf, int k0) {
#pragma unroll
    for (int i = 0; i < 2; ++i) {
      const int o = (tid + i * 512) << 4;  // LDS byte offset within 16 KB tile
      const int r = o >> 9;                // row 0..31 (512 B rows)
      const int cp = (o >> 4) & 31;        // 16B chunk slot within row
      const int g = cp ^ (r & 15);         // global chunk (xor swizzle)
      const u16* gp = Adjb + (size_t)(mbase + r) * NN + k0 + g * 8;
      __builtin_amdgcn_global_load_lds((GLD_AS1*)gp,
                                       (GLD_AS3*)(&Abuf[buf][0] + (o >> 1)), 16, 0, 0);
    }
  };
  auto loadB = [&](int buf, int k0) {
    const int kb = k0 + khalf * 128 + q * 8;
#pragma unroll
    for (int j = 0; j < 4; ++j) {
      breg[buf][0][j] = __builtin_bit_cast(short8, *(const uint4*)(brow0 + kb + j * 32));
      breg[buf][1][j] = __builtin_bit_cast(short8, *(const uint4*)(brow1 + kb + j * 32));
    }
  };

  stageA(0, 0);
  loadB(0, 0);

  for (int t = 0; t < NN / 256; ++t) {
    const int buf = t & 1;
    __syncthreads();  // drains this wave's stage/B loads for tile t (vmcnt), then sync
    if (t + 1 < NN / 256) {
      stageA(buf ^ 1, (t + 1) * 256);
      loadB(buf ^ 1, (t + 1) * 256);
    }
#pragma unroll
    for (int j = 0; j < 4; ++j) {
      const int cp0 = ((khalf * 16 + j * 4 + q) ^ m16) * 8;  // u16 units
      const short8 a0 = *(const short8*)(&Abuf[buf][0] + m16 * 256 + cp0);
      const short8 a1 = *(const short8*)(&Abuf[buf][0] + (16 + m16) * 256 + cp0);
      acc[0][0] = __builtin_amdgcn_mfma_f32_16x16x32_bf16(a0, breg[buf][0][j], acc[0][0], 0, 0, 0);
      acc[0][1] = __builtin_amdgcn_mfma_f32_16x16x32_bf16(a0, breg[buf][1][j], acc[0][1], 0, 0, 0);
      acc[1][0] = __builtin_amdgcn_mfma_f32_16x16x32_bf16(a1, breg[buf][0][j], acc[1][0], 0, 0, 0);
      acc[1][1] = __builtin_amdgcn_mfma_f32_16x16x32_bf16(a1, breg[buf][1][j], acc[1][1], 0, 0, 0);
    }
  }

  // split-K reduction + epilogue
  if (khalf == 1) {
#pragma unroll
    for (int mh = 0; mh < 2; ++mh)
#pragma unroll
      for (int nn = 0; nn < 2; ++nn)
#pragma unroll
        for (int reg = 0; reg < 4; ++reg)
          red[npair][lane][mh * 8 + nn * 4 + reg] = acc[mh][nn][reg];
  }
  __syncthreads();
  if (khalf == 0 && !(OUT_F32 && npair >= 2)) {
#pragma unroll
    for (int mh = 0; mh < 2; ++mh) {
#pragma unroll
      for (int nn = 0; nn < 2; ++nn) {
        const int c = npair * 32 + nn * 16 + m16;
        const float bv = bias[c];
#pragma unroll
        for (int reg = 0; reg < 4; ++reg) {
          const int r = mh * 16 + q * 4 + reg;
          const int gr = mbase + r;
          float sum = acc[mh][nn][reg] + red[npair][lane][mh * 8 + nn * 4 + reg];
          sum += bf2f(Gt[(size_t)c * NN + gr]);  // + I @ u  (A_hat = adj + I)
          sum = dinv[gr] * sum + bv;
          if (RELU) sum = fmaxf(sum, 0.f);
          if (OUT_F32)
            Fout[(size_t)gr * 64 + c] = sum;
          else
            Hout[(size_t)gr * 128 + c] = f2bf(sum);
        }
      }
    }
  }
}

// ---------- launch ----------
extern "C" void kernel_launch(void* const* d_in, const int* in_sizes, int n_in,
                              void* d_out, int out_size, void* d_ws, size_t ws_size,
                              hipStream_t stream) {
  const float* x   = (const float*)d_in[0];  // [8192][64]
  const float* adj = (const float*)d_in[1];  // [8192][8192]
  const float* W0  = (const float*)d_in[2];  // [64][128]
  const float* b0  = (const float*)d_in[3];  // [128]
  const float* W1  = (const float*)d_in[4];  // [128][128]
  const float* b1  = (const float*)d_in[5];  // [128]
  const float* W2  = (const float*)d_in[6];  // [128][64]
  const float* b2  = (const float*)d_in[7];  // [64]
  float* out = (float*)d_out;                // [8192][64] fp32

  char* ws = (char*)d_ws;
  float* dinv = (float*)ws;                          // 32 KB
  u16* Gt     = (u16*)(ws + (1 << 15));              // 2 MB   [128][8192] bf16
  u16* h      = (u16*)(ws + (1 << 15) + (1 << 21));  // 2 MB   [8192][128] bf16
  u16* adjb   = (u16*)(ws + (1 << 23));              // 134 MB [8192][8192] bf16
  // total ws use ~142 MB (ws_size ~1 GiB per harness fill)

  rowsum_cvt_k<<<NN, 256, 0, stream>>>(adj, adjb, dinv);

  // layer 0: u0 = dinv ∘ (x@W0);  h = relu(dinv∘(adjb@u0 + u0) + b0)
  featmul_k<float><<<NN / 16, 256, 0, stream>>>(x, W0, dinv, Gt, 64, 128);
  gcn_gemm<1, 0><<<256, 512, 0, stream>>>(adjb, Gt, dinv, b0, h, nullptr);

  // layer 1
  featmul_k<u16><<<NN / 16, 256, 0, stream>>>(h, W1, dinv, Gt, 128, 128);
  gcn_gemm<1, 0><<<256, 512, 0, stream>>>(adjb, Gt, dinv, b1, h, nullptr);

  // layer 2 (no relu, fp32 out, 64 cols; Gt rows 64..127 are zeros)
  featmul_k<u16><<<NN / 16, 256, 0, stream>>>(h, W2, dinv, Gt, 128, 64);
  gcn_gemm<0, 1><<<256, 512, 0, stream>>>(adjb, Gt, dinv, b2, nullptr, out);
}

// Round 3
// 601.944 us; speedup vs baseline: 1.3640x; 1.1732x over previous
//
#include <hip/hip_runtime.h>
#include <type_traits>

typedef unsigned short u16;
typedef unsigned int   u32;
using short8 = __attribute__((ext_vector_type(8))) short;
using f32x4  = __attribute__((ext_vector_type(4))) float;

#define GLD_AS1 const __attribute__((address_space(1))) unsigned
#define GLD_AS3 __attribute__((address_space(3))) unsigned

static constexpr int NN = 8192;

// ---------- bf16 helpers (manual RNE) ----------
__device__ __forceinline__ u16 f2bf(float f) {
  u32 u = __builtin_bit_cast(u32, f);
  u32 r = (u + 0x7FFFu + ((u >> 16) & 1u)) >> 16;
  return (u16)r;
}
__device__ __forceinline__ float bf2f(u16 h) {
  return __builtin_bit_cast(float, (u32)h << 16);
}
__device__ __forceinline__ short8 cvt8(float4 f0, float4 f1) {
  short8 r;
  r[0] = (short)f2bf(f0.x); r[1] = (short)f2bf(f0.y);
  r[2] = (short)f2bf(f0.z); r[3] = (short)f2bf(f0.w);
  r[4] = (short)f2bf(f1.x); r[5] = (short)f2bf(f1.y);
  r[6] = (short)f2bf(f1.z); r[7] = (short)f2bf(f1.w);
  return r;
}

// ---------- kernel 1: fused rowsum + bf16 convert (16B stores) ----------
__global__ __launch_bounds__(256) void rowsum_cvt_k(const float* __restrict__ adj,
                                                    u16* __restrict__ adjb,
                                                    float* __restrict__ dinv) {
  const int row = blockIdx.x;
  const float4* p = (const float4*)(adj + (size_t)row * NN);
  short8* w = (short8*)(adjb + (size_t)row * NN);
  float s = 0.f;
#pragma unroll
  for (int i = 0; i < 4; ++i) {
    const int idx = threadIdx.x + i * 256;  // pair index 0..1023
    float4 v0 = p[2 * idx];
    float4 v1 = p[2 * idx + 1];
    s += (v0.x + v0.y) + (v0.z + v0.w) + (v1.x + v1.y) + (v1.z + v1.w);
    w[idx] = cvt8(v0, v1);
  }
#pragma unroll
  for (int off = 32; off > 0; off >>= 1) s += __shfl_down(s, off, 64);
  __shared__ float partial[4];
  if ((threadIdx.x & 63) == 0) partial[threadIdx.x >> 6] = s;
  __syncthreads();
  if (threadIdx.x == 0)
    dinv[row] = rsqrtf(partial[0] + partial[1] + partial[2] + partial[3] + 1.0f);
}

// ---------- kernel 2: u = dinv ∘ (X @ W);  Gt[c][r] = bf16(u), U[r][c] = bf16(u)
template <typename TIN>
__global__ __launch_bounds__(256) void featmul_k(const TIN* __restrict__ X,
                                                 const float* __restrict__ W,
                                                 const float* __restrict__ dinv,
                                                 u16* __restrict__ Gt,
                                                 u16* __restrict__ U,
                                                 int K, int C) {
  __shared__ __align__(16) u16 Wt[128][128];
  __shared__ float red[4][16][32];
  const int tid = threadIdx.x;
  for (int idx = tid; idx < 128 * 128; idx += 256) {
    int c = idx & 127, k = idx >> 7;
    float w = (k < K && c < C) ? W[k * C + c] : 0.f;
    Wt[c][k] = f2bf(w);
  }
  __syncthreads();
  const int wv = tid >> 6, lane = tid & 63;
  const int q = lane >> 4, m16 = lane & 15;
  const int r0 = blockIdx.x * 16;
  const int c0 = wv * 32;
  f32x4 acc[2];
  acc[0] = {0.f, 0.f, 0.f, 0.f};
  acc[1] = {0.f, 0.f, 0.f, 0.f};
  const TIN* xrow = X + (size_t)(r0 + m16) * K;
  for (int k = 0; k < K; k += 32) {
    short8 af;
    if constexpr (std::is_same_v<TIN, float>) {
      float4 f0 = *(const float4*)(xrow + k + q * 8);
      float4 f1 = *(const float4*)(xrow + k + q * 8 + 4);
      af = cvt8(f0, f1);
    } else {
      af = __builtin_bit_cast(short8, *(const uint4*)(xrow + k + q * 8));
    }
#pragma unroll
    for (int nh = 0; nh < 2; ++nh) {
      short8 bf = *(const short8*)&Wt[c0 + nh * 16 + m16][k + q * 8];
      acc[nh] = __builtin_amdgcn_mfma_f32_16x16x32_bf16(af, bf, acc[nh], 0, 0, 0);
    }
  }
#pragma unroll
  for (int nh = 0; nh < 2; ++nh)
#pragma unroll
    for (int reg = 0; reg < 4; ++reg)
      red[wv][q * 4 + reg][nh * 16 + m16] = acc[nh][reg];
  __syncthreads();
  {
    const int cc = lane & 31, rh = lane >> 5;
    short8 t;
#pragma unroll
    for (int i = 0; i < 8; ++i) {
      int r = rh * 8 + i;
      t[i] = (short)f2bf(red[wv][r][cc] * dinv[r0 + r]);
      U[(size_t)(r0 + r) * 128 + c0 + cc] = (u16)t[i];
    }
    *(uint4*)(Gt + (size_t)(c0 + cc) * NN + r0 + rh * 8) = __builtin_bit_cast(uint4, t);
  }
}

// ---------- kernel 3: partial GEMM  P[ks] = adjb[mtile, krange] @ Gt^T[krange, :]
// 128x128 block tile, BK=64, A+B staged via global_load_lds(16) with xor swizzle.
// grid (64 mtiles, 8 ksplits) = 512 blocks (2/CU). 256 thr = 4 waves in 2x2,
// each wave 64x64 (4x4 16x16x32 mfma tiles). A loads tagged nt (stream-once).
__global__ __launch_bounds__(256, 2) void gcn_gemm(const u16* __restrict__ Adjb,
                                                   const u16* __restrict__ Gt,
                                                   float* __restrict__ P) {
  __shared__ __align__(16) u16 As[2][128 * 64];  // 16 KB each buf
  __shared__ __align__(16) u16 Bs[2][128 * 64];

  const int tid = threadIdx.x;
  const int wv = tid >> 6, lane = tid & 63;
  const int wm = wv >> 1, wn = wv & 1;
  const int q = lane >> 4, m16 = lane & 15;
  const int mbase = blockIdx.x * 128;
  const int kbase = blockIdx.y * 1024;
  float* Pt = P + (size_t)blockIdx.y * NN * 128;

  auto stage = [&](int buf, int kc) {
#pragma unroll
    for (int i = 0; i < 4; ++i) {
      const int cl = i * 256 + tid;       // chunk-linear 0..1023
      const int r = cl >> 3;              // row 0..127 (8 chunks/row)
      const int g = (cl & 7) ^ (r & 7);   // xor-swizzled global chunk
      const u16* ga = Adjb + (size_t)(mbase + r) * NN + kc + g * 8;
      const u16* gb = Gt + (size_t)r * NN + kc + g * 8;
      __builtin_amdgcn_global_load_lds((GLD_AS1*)ga, (GLD_AS3*)(&As[buf][cl * 8]), 16, 0, 2);
      __builtin_amdgcn_global_load_lds((GLD_AS1*)gb, (GLD_AS3*)(&Bs[buf][cl * 8]), 16, 0, 0);
    }
  };

  f32x4 acc[4][4];
#pragma unroll
  for (int a = 0; a < 4; ++a)
#pragma unroll
    for (int b = 0; b < 4; ++b) acc[a][b] = {0.f, 0.f, 0.f, 0.f};

  stage(0, kbase);
  for (int t = 0; t < 16; ++t) {
    const int buf = t & 1;
    __syncthreads();  // drains stage(t); other block on this CU keeps pipe busy
    if (t < 15) stage(buf ^ 1, kbase + (t + 1) * 64);
#pragma unroll
    for (int j = 0; j < 2; ++j) {
      short8 af[4], bf[4];
#pragma unroll
      for (int i = 0; i < 4; ++i) {
        const int m = wm * 64 + i * 16 + m16;
        const int n = wn * 64 + i * 16 + m16;
        af[i] = *(const short8*)&As[buf][m * 64 + (((j * 4 + q) ^ (m & 7)) << 3)];
        bf[i] = *(const short8*)&Bs[buf][n * 64 + (((j * 4 + q) ^ (n & 7)) << 3)];
      }
#pragma unroll
      for (int a = 0; a < 4; ++a)
#pragma unroll
        for (int b = 0; b < 4; ++b)
          acc[a][b] = __builtin_amdgcn_mfma_f32_16x16x32_bf16(af[a], bf[b], acc[a][b], 0, 0, 0);
    }
  }

  // write 128x128 fp32 partial tile (disjoint per block; no init needed)
#pragma unroll
  for (int a = 0; a < 4; ++a) {
#pragma unroll
    for (int b = 0; b < 4; ++b) {
      const int c = wn * 64 + b * 16 + m16;
#pragma unroll
      for (int reg = 0; reg < 4; ++reg) {
        const int r = mbase + wm * 64 + a * 16 + q * 4 + reg;
        Pt[(size_t)r * 128 + c] = acc[a][b][reg];
      }
    }
  }
}

// ---------- kernel 4: finalize  out = ep( dinv[r]*(sum_s P[s] + u) + bias ) ----
template <int RELU, int OUT_F32>
__global__ __launch_bounds__(256) void finalize_k(const float* __restrict__ P,
                                                  const u16* __restrict__ U,
                                                  const float* __restrict__ dinv,
                                                  const float* __restrict__ bias,
                                                  u16* __restrict__ Hout,
                                                  float* __restrict__ Fout) {
  const int tid = threadIdx.x;
  const int c = tid & 127;
  const int r = blockIdx.x * 2 + (tid >> 7);
  const size_t idx = (size_t)r * 128 + c;
  float s = 0.f;
#pragma unroll
  for (int k = 0; k < 8; ++k) s += P[(size_t)k * NN * 128 + idx];
  s += bf2f(U[idx]);
  s = dinv[r] * s + bias[c];
  if (RELU) s = fmaxf(s, 0.f);
  if (OUT_F32) {
    if (c < 64) Fout[(size_t)r * 64 + c] = s;
  } else {
    Hout[idx] = f2bf(s);
  }
}

// ---------- launch ----------
extern "C" void kernel_launch(void* const* d_in, const int* in_sizes, int n_in,
                              void* d_out, int out_size, void* d_ws, size_t ws_size,
                              hipStream_t stream) {
  const float* x   = (const float*)d_in[0];  // [8192][64]
  const float* adj = (const float*)d_in[1];  // [8192][8192]
  const float* W0  = (const float*)d_in[2];  // [64][128]
  const float* b0  = (const float*)d_in[3];  // [128]
  const float* W1  = (const float*)d_in[4];  // [128][128]
  const float* b1  = (const float*)d_in[5];  // [128]
  const float* W2  = (const float*)d_in[6];  // [128][64]
  const float* b2  = (const float*)d_in[7];  // [64]
  float* out = (float*)d_out;                // [8192][64] fp32

  char* ws = (char*)d_ws;
  float* dinv = (float*)ws;                      // 32 KB   @ 0
  u16* Gt     = (u16*)(ws + (1u << 20));         // 2 MB    @ 1 MB   [128][8192]
  u16* U      = (u16*)(ws + (4u << 20));         // 2 MB    @ 4 MB   [8192][128]
  u16* h      = (u16*)(ws + (6u << 20));         // 2 MB    @ 6 MB   [8192][128]
  float* Pp   = (float*)(ws + (8u << 20));       // 32 MB   @ 8 MB   [8][8192][128] fp32
  u16* adjb   = (u16*)(ws + (48u << 20));        // 134 MB  @ 48 MB  [8192][8192]

  const dim3 ggrid(64, 8);

  rowsum_cvt_k<<<NN, 256, 0, stream>>>(adj, adjb, dinv);

  // layer 0
  featmul_k<float><<<NN / 16, 256, 0, stream>>>(x, W0, dinv, Gt, U, 64, 128);
  gcn_gemm<<<ggrid, 256, 0, stream>>>(adjb, Gt, Pp);
  finalize_k<1, 0><<<NN / 2, 256, 0, stream>>>(Pp, U, dinv, b0, h, nullptr);

  // layer 1
  featmul_k<u16><<<NN / 16, 256, 0, stream>>>(h, W1, dinv, Gt, U, 128, 128);
  gcn_gemm<<<ggrid, 256, 0, stream>>>(adjb, Gt, Pp);
  finalize_k<1, 0><<<NN / 2, 256, 0, stream>>>(Pp, U, dinv, b1, h, nullptr);

  // layer 2 (identity act, fp32 out, cols 64..127 of Gt/U are zero)
  featmul_k<u16><<<NN / 16, 256, 0, stream>>>(h, W2, dinv, Gt, U, 128, 64);
  gcn_gemm<<<ggrid, 256, 0, stream>>>(adjb, Gt, Pp);
  finalize_k<0, 1><<<NN / 2, 256, 0, stream>>>(Pp, U, dinv, b2, nullptr, out);
}